// Round 5
// baseline (265.141 us; speedup 1.0000x reference)
//
#include <hip/hip_runtime.h>
#include <math.h>

// FilterDetection: score threshold + morphological opening (erode 4x4,
// dilate 4x4) on 32x1024x1024 f32.
//
// Round-12 design: forced-MLP + aligned loads + shfl halo.
//   Round-3 post-mortem: VGPR=48 proves the compiler sank the prefetch
//   (state alone is 48 regs) in BOTH rounds 10 and 11 -> neither ILP nor
//   TLP was ever actually tested; all variants ran load->use serialized at
//   ~2.85 TB/s, VALUBusy 14%. This round pins the scheduler's occupancy
//   target with amdgpu_waves_per_eu(4,4) (128-VGPR budget, no benefit to
//   shrinking below it) and holds a REAL 3-deep row prefetch in registers.
//   Loads are now per-lane aligned non-overlapping float4 (lane's own 4
//   cols); the 6 halo floats come from neighbor lanes via __shfl_up/down
//   (in-register, no LDS, no barriers); the wave-seam words (lane 0 left,
//   lane 63 right) come from one exec-masked 2-lane float4 load. ~2.4x
//   fewer L1 line transactions per row, same HBM bytes.
//   Score blocks moved to the FRONT of the grid (tail no longer serial).
//
// (Round 4: identical resubmit — round-12 never ran, broker timeout.)
//
// Kept: 4 cols/lane, 256-col segments, 2048 mask blocks (4 waves of a block
// = 4 segments of one strip); XCD-chunked bijective swizzle; two-level
// sliding min/max pipelines; row-clamped addresses + uniform OOB fold;
// threshold deferred to store (monotone; absmax=0 rounds 1-11); stores
// strictly inside strip; plain coherent stores.
//
// Window geometry (from lax.reduce_window padding):
//   erode : offsets [-2..+1] both axes, OOB = +inf
//   dilate: offsets [-1..+2] both axes, OOB = -inf
// Per lane (4 out cols c0..c0+3): raw c0-3..c0+6 (10), eroded c0-1..c0+5 (7).

#define H 1024
#define W 1024
#define R 16
#define STRIPS (H / R)                    // 64
#define SEGS 4                            // 256-col segments per row
#define BATCH 32
#define TASKS (STRIPS * SEGS * BATCH)     // 8192 wave-tasks
#define MASK_BLOCKS (TASKS / 4)           // 2048 blocks, 4 waves each
#define N_SCORE 32000
#define SCORE_BLOCKS ((N_SCORE + 255) / 256)  // 125
#define ITERS (R + 6)                     // 22 row-iterations per wave

__device__ __forceinline__ float th(float v) { return v >= 0.5f ? v : 0.0f; }

__global__ __launch_bounds__(256)
__attribute__((amdgpu_waves_per_eu(4, 4)))   // pin scheduler to 128-VGPR budget
void fused_kernel(const float* __restrict__ score,
                  const float* __restrict__ mask,
                  float* __restrict__ out) {
    const int bid0 = blockIdx.x;
    const int tid  = threadIdx.x;

    if (bid0 < SCORE_BLOCKS) {              // score threshold, dispatched first
        int i = bid0 * 256 + tid;
        if (i < N_SCORE) out[i] = th(score[i]);
        return;
    }
    const int mb0 = bid0 - SCORE_BLOCKS;

    // XCD swizzle: contiguous chunk of 256 blocks per XCD for halo L2 reuse.
    const int bid = (mb0 & 7) * (MASK_BLOCKS / 8) + (mb0 >> 3);

    const int wave = tid >> 6;
    const int lane = tid & 63;
    const int task = bid * 4 + wave;        // one wave = one (img,strip,seg)
    const int b    = task >> 8;             // 256 tasks per image
    const int rem  = task & 255;
    const int strip= rem >> 2;              // 4 waves of a block share strip
    const int seg  = rem & 3;
    const int y0   = strip * R;
    const int c0   = seg * 256 + lane * 4;  // first of this lane's 4 columns

    const float* img  = mask + (size_t)b * (H * W);
    float*       outp = out + N_SCORE + (size_t)b * (H * W);

    const bool eL = (c0 == 0);              // image-left lane (cols <0 pad)
    const bool eR = (c0 == W - 4);          // image-right lane (cols >=W pad)
    const bool sm = (lane == 0) || (lane == 63);   // seam lanes
    // Seam word address (clamped; edge lanes' values overridden by eL/eR):
    const int oS = (lane == 0) ? (eL ? 0 : c0 - 4)
                               : (eR ? W - 4 : c0 + 4);

    // 3-deep prefetch buffers, compile-time indexed under full unroll.
    // own[s] = lane's 4 cols; seam[s]: lane0 holds left word, lane63 right.
    float4 own[3], seam[3];

#define ISSUE(IT) do {                                                   \
        int t_  = y0 - 3 + (IT);                                         \
        int tc_ = t_ < 0 ? 0 : (t_ >= H ? H - 1 : t_);   /* uniform */   \
        const float* row_ = img + (size_t)tc_ * W;                       \
        own[(IT) % 3] = *(const float4*)(row_ + c0);                     \
        if (sm) seam[(IT) % 3] = *(const float4*)(row_ + oS);            \
    } while (0)

    ISSUE(0); ISSUE(1); ISSUE(2);

    // Vertical-min pipeline over hmin rows (window t-3..t), 7 eroded cols:
    float hmP[7], q1[7], q2[7];
    #pragma unroll
    for (int m = 0; m < 7; ++m) { hmP[m] = q1[m] = q2[m] = INFINITY; }
    // Vertical-max pipeline over hmax rows (window r-3..r), 4 out cols:
    float hxP[4], u1[4], u2[4];
    #pragma unroll
    for (int j = 0; j < 4; ++j)  { hxP[j] = u1[j] = u2[j] = -INFINITY; }

    #pragma unroll
    for (int it = 0; it < ITERS; ++it) {
        const int t   = y0 - 3 + it;        // raw row consumed this iteration
        const int buf = it % 3;
        const bool rowOK = (t >= 0) && (t < H);            // wave-uniform

        // ---- assemble raw cols c0-3..c0+6 from own + neighbor lanes ----
        float4 ow = own[buf];
        float4 sw = seam[buf];
        float a0 = __shfl_up(ow.y, 1);      // col c0-3 (neighbor's c0-4+1)
        float a1 = __shfl_up(ow.z, 1);      // col c0-2
        float a2 = __shfl_up(ow.w, 1);      // col c0-1
        float a7 = __shfl_down(ow.x, 1);    // col c0+4
        float a8 = __shfl_down(ow.y, 1);    // col c0+5
        float a9 = __shfl_down(ow.z, 1);    // col c0+6
        // wave-seam lanes take the halo from their private seam word:
        a0 = (lane == 0)  ? sw.y : a0;
        a1 = (lane == 0)  ? sw.z : a1;
        a2 = (lane == 0)  ? sw.w : a2;
        a7 = (lane == 63) ? sw.x : a7;
        a8 = (lane == 63) ? sw.y : a8;
        a9 = (lane == 63) ? sw.z : a9;
        // image-edge pad (+inf, erosion identity):
        float ar[10];
        ar[0] = eL ? INFINITY : a0;
        ar[1] = eL ? INFINITY : a1;
        ar[2] = eL ? INFINITY : a2;
        ar[3] = ow.x;  ar[4] = ow.y;  ar[5] = ow.z;  ar[6] = ow.w;
        ar[7] = eR ? INFINITY : a7;
        ar[8] = eR ? INFINITY : a8;
        ar[9] = eR ? INFINITY : a9;

        // ---- prefetch row it+3 into the slot just freed ----
        if (it + 3 < ITERS) ISSUE(it + 3);

        // ---- hmin row t via shared pairwise mins; fold OOB row to +inf ----
        float p[9];
        #pragma unroll
        for (int m = 0; m < 9; ++m) p[m] = fminf(ar[m], ar[m + 1]);
        float hm[7];
        #pragma unroll
        for (int m = 0; m < 7; ++m) {
            float v = fminf(p[m], p[m + 2]);
            hm[m] = rowOK ? v : INFINITY;    // erosion pad for OOB raw rows
        }

        // ---- eroded row r = t-1: min over hm rows t-3..t = min(qt, q2) ----
        const int r = t - 1;
        const float rlim = (r >= 0 && r < H) ? INFINITY : -INFINITY;  // uniform
        float qt[7], ec[7];
        #pragma unroll
        for (int m = 0; m < 7; ++m) {
            qt[m] = fminf(hmP[m], hm[m]);
            ec[m] = fminf(fminf(qt[m], q2[m]), rlim);
        }
        // Column pad (-inf), image-edge lanes only:
        //   eL: eroded col -1; eR: eroded cols 1024, 1025.
        ec[0] = eL ? -INFINITY : ec[0];
        ec[5] = eR ? -INFINITY : ec[5];
        ec[6] = eR ? -INFINITY : ec[6];

        // shift min pipeline (renamed under full unroll)
        #pragma unroll
        for (int m = 0; m < 7; ++m) { q2[m] = q1[m]; q1[m] = qt[m]; hmP[m] = hm[m]; }

        // ---- hmax row r via shared pairwise maxes; start vertical max ----
        float p2[6];
        #pragma unroll
        for (int j = 0; j < 6; ++j) p2[j] = fmaxf(ec[j], ec[j + 1]);
        float hx[4], ur[4];
        #pragma unroll
        for (int j = 0; j < 4; ++j) {
            hx[j] = fmaxf(p2[j], p2[j + 2]);       // hmax col c0+j, row r
            ur[j] = fmaxf(hxP[j], hx[j]);          // max(hx_r, hx_{r-1})
        }

        // ---- output row y = t-3: max over hx rows y-1..y+2 = max(ur, u2) ----
        if (it >= 6) {                       // strictly inside the strip
            const int y = t - 3;
            float o[4];
            #pragma unroll
            for (int j = 0; j < 4; ++j)
                o[j] = th(fmaxf(ur[j], u2[j]));
            float* po = outp + (size_t)y * W + c0;
            *(float4*)(po) = make_float4(o[0], o[1], o[2], o[3]);
        }

        // shift max pipeline
        #pragma unroll
        for (int j = 0; j < 4; ++j) { u2[j] = u1[j]; u1[j] = ur[j]; hxP[j] = hx[j]; }
    }
#undef ISSUE
}

extern "C" void kernel_launch(void* const* d_in, const int* in_sizes, int n_in,
                              void* d_out, int out_size, void* d_ws, size_t ws_size,
                              hipStream_t stream) {
    const float* score = (const float*)d_in[0];
    const float* mask  = (const float*)d_in[1];
    float* out = (float*)d_out;

    const int grid = MASK_BLOCKS + SCORE_BLOCKS;
    fused_kernel<<<grid, 256, 0, stream>>>(score, mask, out);
}

// Round 6
// 248.921 us; speedup vs baseline: 1.0652x; 1.0652x over previous
//
#include <hip/hip_runtime.h>
#include <math.h>

// FilterDetection: score threshold + morphological opening (erode 4x4,
// dilate 4x4) on 32x1024x1024 f32.
//
// Round-13 design: LDS row pipeline via global_load_lds + counted vmcnt.
//   Rounds 9-12 post-mortem: dur pinned at 104-106us across 4 structures;
//   FETCH cut 27% with no dur change (not BW-bound); VGPR pinned 48-64 by
//   the allocator -> register prefetch always sunk -> ~0.3 loads in flight
//   per wave (Little's law at 2.55 TB/s). Fix: move the pipeline into LDS
//   with __builtin_amdgcn_global_load_lds (HBM->LDS direct, compiler cannot
//   sink it) + raw s_barrier + counted s_waitcnt vmcnt(K) (NEVER
//   __syncthreads in the loop - it drains vmcnt to 0, killing the pipe).
//
//   Block = one (img, strip): 16 output rows x 1024 cols. 4-slot LDS row
//   ring [4 +inf pad | 1024 | 4 +inf pad] (16.5 KB -> exactly 8 blocks/CU).
//   Stage: each wave issues ONE global_load_lds_dwordx4 (1 KB) per row;
//   4 waves cover the 4 KB row. Consume: 3 aligned ds_read_b128 per lane
//   (cols c0-4..c0+7); LDS side pads make all column-halo logic vanish
//   (no shuffles, no seam loads, no edge selects on the erode side).
//   Stage depth 2 (stage row it+2 while consuming it); slot reuse distance
//   3 mod 4 != 0 -> single barrier per row is race-free. Exact per-row
//   vmcnt counts (stages+stores, in-order counter) keep >= 2 rows in
//   flight per wave across barriers.
//
// Kept: XCD-chunked bijective swizzle (adjacent strips -> same XCD L2 for
// the 6 halo rows); two-level sliding min/max pipelines; row-clamped
// staging + uniform OOB fold; threshold deferred to store (monotone;
// absmax=0 rounds 1-12); stores strictly inside strip; score blocks first.
//
// Window geometry (from lax.reduce_window padding):
//   erode : offsets [-2..+1] both axes, OOB = +inf
//   dilate: offsets [-1..+2] both axes, OOB = -inf
// Output row y needs raw rows y-3..y+3; output col j needs raw j-3..j+3.

#define H 1024
#define W 1024
#define R 16
#define STRIPS (H / R)                    // 64
#define BATCH 32
#define MASK_BLOCKS (STRIPS * BATCH)      // 2048 blocks: one per (img,strip)
#define N_SCORE 32000
#define SCORE_BLOCKS ((N_SCORE + 255) / 256)  // 125
#define ITERS (R + 6)                     // 22 raw rows per strip
#define LROW 1032                         // LDS row: 4 pad | 1024 | 4 pad
#define NSLOT 4

__device__ __forceinline__ float th(float v) { return v >= 0.5f ? v : 0.0f; }

__global__ __launch_bounds__(256)
void fused_kernel(const float* __restrict__ score,
                  const float* __restrict__ mask,
                  float* __restrict__ out) {
    const int bid0 = blockIdx.x;
    const int tid  = threadIdx.x;

    if (bid0 < SCORE_BLOCKS) {              // score threshold, dispatched first
        int i = bid0 * 256 + tid;
        if (i < N_SCORE) out[i] = th(score[i]);
        return;
    }
    const int mb0 = bid0 - SCORE_BLOCKS;
    // XCD swizzle: 256-block chunk per XCD (= 4 whole images, strips in
    // order) so adjacent strips' 6 shared halo rows hit the same L2.
    const int bid = (mb0 & 7) * (MASK_BLOCKS / 8) + (mb0 >> 3);

    const int b     = bid >> 6;             // image
    const int strip = bid & 63;
    const int y0    = strip * R;
    const int wave  = tid >> 6;
    const int c0    = tid * 4;              // this thread's 4 output cols

    const float* img  = mask + (size_t)b * (H * W);
    float*       outp = out + N_SCORE + (size_t)b * (H * W);

    __shared__ float smem[NSLOT * LROW];    // 16512 B -> 8 blocks/CU

    // +inf side pads (erosion identity), once per slot. 8 pads x 4 slots.
    if (tid < 8 * NSLOT) {
        int s = tid >> 3, k = tid & 7;
        smem[s * LROW + (k < 4 ? k : 1024 + k)] = INFINITY;  // 0..3 / 1028..1031
    }
    __syncthreads();                        // full drain OK (once, pre-loop)

    const bool eL = (tid == 0);             // image-left column edge
    const bool eR = (tid == 255);           // image-right column edge

    // ---- stage raw row (y0-3+IT), clamped, into slot IT&3 ----
#define STAGE(IT) do {                                                        \
        int t_  = y0 - 3 + (IT);                                              \
        int tc_ = t_ < 0 ? 0 : (t_ > H - 1 ? H - 1 : t_);  /* uniform */      \
        const float* gsrc = img + (size_t)tc_ * W + c0;    /* lane*16B */     \
        float* ldst = &smem[((IT) & 3) * LROW + 4 + (wave << 8)]; /* wave-uniform */ \
        __builtin_amdgcn_global_load_lds(                                     \
            (const __attribute__((address_space(1))) void*)gsrc,              \
            (__attribute__((address_space(3))) void*)ldst, 16, 0, 0);         \
    } while (0)

    // Vertical-min pipeline over hmin rows (window t-3..t), 7 eroded cols:
    float hmP[7], q1[7], q2[7];
    for (int m = 0; m < 7; ++m) { hmP[m] = q1[m] = q2[m] = INFINITY; }
    // Vertical-max pipeline over hmax rows (window r-3..r), 4 out cols:
    float hxP[4], u1[4], u2[4];
    for (int j = 0; j < 4; ++j)  { hxP[j] = u1[j] = u2[j] = -INFINITY; }

    STAGE(0); STAGE(1);                     // prologue: depth-2 pipeline

    // One step: stage row IT+2, wait for row IT (counted, in-order vmcnt:
    // newer ops = stages IT+1,IT+2 (if <ITERS) + stores IT-2,IT-1 (if >=6)),
    // barrier, consume row IT from LDS, compute, store output row IT-6.
#define STEP(IT) do {                                                         \
        if ((IT) + 2 < ITERS) STAGE((IT) + 2);                                \
        { constexpr int K_ = ((IT) + 1 < ITERS ? 1 : 0)                       \
                           + ((IT) + 2 < ITERS ? 1 : 0)                       \
                           + ((IT) >= 7 ? 1 : 0) + ((IT) >= 8 ? 1 : 0);       \
          asm volatile("s_waitcnt vmcnt(%0)" :: "i"(K_) : "memory"); }        \
        __builtin_amdgcn_s_barrier();                                         \
        __builtin_amdgcn_sched_barrier(0);                                    \
        {                                                                     \
            const int t = y0 - 3 + (IT);                                      \
            const bool rowOK = (t >= 0) && (t < H);        /* uniform */      \
            const float* ls = &smem[((IT) & 3) * LROW + c0];                  \
            float4 L0 = *(const float4*)(ls);      /* cols c0-4..c0-1 */      \
            float4 L1 = *(const float4*)(ls + 4);  /* cols c0  ..c0+3 */      \
            float4 L2 = *(const float4*)(ls + 8);  /* cols c0+4..c0+7 */      \
            float ar[10];                                                     \
            ar[0] = L0.y; ar[1] = L0.z; ar[2] = L0.w;                         \
            ar[3] = L1.x; ar[4] = L1.y; ar[5] = L1.z; ar[6] = L1.w;           \
            ar[7] = L2.x; ar[8] = L2.y; ar[9] = L2.z;                         \
            float p[9];                                                       \
            for (int m = 0; m < 9; ++m) p[m] = fminf(ar[m], ar[m + 1]);       \
            float hm[7];                                                      \
            for (int m = 0; m < 7; ++m) {                                     \
                float v = fminf(p[m], p[m + 2]);                              \
                hm[m] = rowOK ? v : INFINITY;   /* erosion row pad */         \
            }                                                                 \
            const int r = t - 1;                                              \
            const float rlim = (r >= 0 && r < H) ? INFINITY : -INFINITY;      \
            float qt[7], ec[7];                                               \
            for (int m = 0; m < 7; ++m) {                                     \
                qt[m] = fminf(hmP[m], hm[m]);                                 \
                ec[m] = fminf(fminf(qt[m], q2[m]), rlim);                     \
            }                                                                 \
            ec[0] = eL ? -INFINITY : ec[0];     /* eroded col -1    */        \
            ec[5] = eR ? -INFINITY : ec[5];     /* eroded col 1024  */        \
            ec[6] = eR ? -INFINITY : ec[6];     /* eroded col 1025  */        \
            for (int m = 0; m < 7; ++m) { q2[m] = q1[m]; q1[m] = qt[m]; hmP[m] = hm[m]; } \
            float p2[6];                                                      \
            for (int j = 0; j < 6; ++j) p2[j] = fmaxf(ec[j], ec[j + 1]);      \
            float hx[4], ur[4];                                               \
            for (int j = 0; j < 4; ++j) {                                     \
                hx[j] = fmaxf(p2[j], p2[j + 2]);                              \
                ur[j] = fmaxf(hxP[j], hx[j]);                                 \
            }                                                                 \
            if ((IT) >= 6) {                                                  \
                const int y = t - 3;                                          \
                float o0 = th(fmaxf(ur[0], u2[0]));                           \
                float o1 = th(fmaxf(ur[1], u2[1]));                           \
                float o2 = th(fmaxf(ur[2], u2[2]));                           \
                float o3 = th(fmaxf(ur[3], u2[3]));                           \
                *(float4*)(outp + (size_t)y * W + c0) =                       \
                    make_float4(o0, o1, o2, o3);                              \
            }                                                                 \
            for (int j = 0; j < 4; ++j) { u2[j] = u1[j]; u1[j] = ur[j]; hxP[j] = hx[j]; } \
        }                                                                     \
    } while (0)

    STEP(0);  STEP(1);  STEP(2);  STEP(3);  STEP(4);  STEP(5);
    STEP(6);  STEP(7);  STEP(8);  STEP(9);  STEP(10); STEP(11);
    STEP(12); STEP(13); STEP(14); STEP(15); STEP(16); STEP(17);
    STEP(18); STEP(19); STEP(20); STEP(21);

#undef STEP
#undef STAGE
}

extern "C" void kernel_launch(void* const* d_in, const int* in_sizes, int n_in,
                              void* d_out, int out_size, void* d_ws, size_t ws_size,
                              hipStream_t stream) {
    const float* score = (const float*)d_in[0];
    const float* mask  = (const float*)d_in[1];
    float* out = (float*)d_out;

    const int grid = MASK_BLOCKS + SCORE_BLOCKS;
    fused_kernel<<<grid, 256, 0, stream>>>(score, mask, out);
}